// Round 15
// baseline (221.274 us; speedup 1.0000x reference)
//
#include <hip/hip_runtime.h>

// HetGNN fused kernel, round 15: 32x32 MFMA restructure -- 4 graphs per wave
// tile, halving the serial stage count (the ~50%-idle chain R10/R11 couldn't
// fix). C/D mapping: col=lane&31, row=(reg&3)+8*(reg>>2)+4*(lane>>5) (HW-
// verified); A/B: m|n=lane&31, k=8*(lane>>5)+j per K=16 chunk.
// LDS fit: W51/W71 (K=128 mats) move to d_ws as pre-swizzled bf16 B-frags
// (setup kernel; coalesced global dwordx4 on the idle VMEM pipe, L2-hot) ->
// sW 64 KB + act 8x10 KB + consts = 151.8 KB. Epilogue = post-MFMA against
// zero-padded wpost B-frag (no shuffle butterfly).
// Carried: merged M buffer, b61-folded aPb, 3-neighbor mlp6 (no diagonal),
// v_perm pack, raw pkmax with final clamp-0.

typedef unsigned short u16;
typedef unsigned int   u32;
typedef __attribute__((ext_vector_type(8)))  short short8_t;
typedef __attribute__((ext_vector_type(2)))  short short2v;
typedef __attribute__((ext_vector_type(16))) float float16v;

// sW u16 offsets: 64x64 matrices, 8 frags each at (t*4+c)*512.
#define W61A 0
#define W61B 4096
#define W52o 8192
#define W53o 12288
#define W62o 16384
#define W63o 20480
#define W72o 24576
#define W73o 28672
#define SW_U16 32768

// d_ws: W51 frags 0..15, W71 frags 16..31; frag (mi*16 + t*8 + c8)*512 u16.

// sConst f32 offsets
#define CB51 0
#define CB52 64
#define CB53 128
#define CB61 192
#define CB62 256
#define CB63 320
#define CB71 384
#define CB72 448
#define CB73 512
#define CWPO 576
#define CBPO 704
#define CWPA 768
#define CBPA 832
#define CWPE 896
#define CBPE 1024
#define CSZ  1088

#define PW_U16 5120   // per-wave: M 2048 | T1 2048 | aPb 1024

struct Params {
  const float *ap, *ef;
  const float *wpa, *bpa, *wpe, *bpe;
  const float *w51, *b51, *w52, *b52, *w53, *b53;
  const float *w61, *b61, *w62, *b62, *w63, *b63;
  const float *w71, *b71, *w72, *b72, *w73, *b73;
  const float *wpost, *bpost;
  float *out;
  u16 *ws;
  int gtot;
};

__device__ __forceinline__ u32 f2bf_up(float f) {
  return (__float_as_uint(f) + 0x8000u) >> 16;   // round-half-up, single
}
__device__ __forceinline__ u32 pk2(float a, float b) {
  const u32 ua = __float_as_uint(a) + 0x8000u;
  const u32 ub = __float_as_uint(b) + 0x8000u;
  return __builtin_amdgcn_perm(ub, ua, 0x07060302u);  // {ub[31:16], ua[31:16]}
}
__device__ __forceinline__ float blo(u32 v) { return __uint_as_float(v << 16); }
__device__ __forceinline__ float bhi(u32 v) { return __uint_as_float(v & 0xffff0000u); }
__device__ __forceinline__ u32 pkmax(u32 a, u32 b) {
  const short2v r = __builtin_elementwise_max(__builtin_bit_cast(short2v, a),
                                              __builtin_bit_cast(short2v, b));
  return __builtin_bit_cast(u32, r);
}
__device__ __forceinline__ u32 ror16(u32 x) { return (x >> 16) | (x << 16); }

__device__ __forceinline__ float16v mfma32(short8_t a, short8_t b, float16v c) {
  return __builtin_amdgcn_mfma_f32_32x32x16_bf16(a, b, c, 0, 0, 0);
}
__device__ __forceinline__ void initv(float16v* acc, const float* cb, int lo) {
#pragma unroll
  for (int t = 0; t < 2; ++t) {
    const float b = cb[32 * t + lo];
#pragma unroll
    for (int i = 0; i < 16; ++i) acc[t][i] = b;
  }
}
__device__ __forceinline__ void zerov(float16v* acc) {
#pragma unroll
  for (int t = 0; t < 2; ++t)
#pragma unroll
    for (int i = 0; i < 16; ++i) acc[t][i] = 0.f;
}
__device__ __forceinline__ void gather4(short8_t* x, const u16* src, int l) {
#pragma unroll
  for (int c = 0; c < 4; ++c) x[c] = *(const short8_t*)(src + c * 512 + l * 8);
}
__device__ __forceinline__ void layer64(float16v* acc, const short8_t* A,
                                        const u16* B, int l) {
#pragma unroll
  for (int t = 0; t < 2; ++t)
#pragma unroll
    for (int c = 0; c < 4; ++c)
      acc[t] = mfma32(A[c], *(const short8_t*)(B + (t * 4 + c) * 512 + l * 8), acc[t]);
}

// C-regs -> A-swizzled 32-row bf16 buffer. addr = c*512 + h'*256 + m*8 + j,
// c=f>>4, h'=(f>>3)&1, j=f&7; lane col f0 = 32t + lo.
template<bool RELU>
__device__ __forceinline__ void scat32(u16* dst, const float16v* acc, int lo, int hh) {
#pragma unroll
  for (int t = 0; t < 2; ++t) {
    u16* base = dst + (2 * t + (lo >> 4)) * 512 + ((lo >> 3) & 1) * 256 + (lo & 7);
#pragma unroll
    for (int i = 0; i < 8; ++i) {
      const int row0 = ((2 * i) & 3) + 8 * (i >> 1) + 4 * hh;
      float v0 = acc[t][2 * i], v1 = acc[t][2 * i + 1];
      if (RELU) { v0 = fmaxf(v0, 0.f); v1 = fmaxf(v1, 0.f); }
      const u32 v = pk2(v0, v1);
      base[row0 * 8] = (u16)v;
      base[(row0 + 1) * 8] = (u16)(v >> 16);
    }
  }
}
__device__ __forceinline__ void scatpk32(u16* dst, const u32* s, int lo, int hh) {
#pragma unroll
  for (int t = 0; t < 2; ++t) {
    u16* base = dst + (2 * t + (lo >> 4)) * 512 + ((lo >> 3) & 1) * 256 + (lo & 7);
#pragma unroll
    for (int i = 0; i < 8; ++i) {
      const int row0 = ((2 * i) & 3) + 8 * (i >> 1) + 4 * hh;
      const u32 v = s[t * 8 + i];
      base[row0 * 8] = (u16)v;
      base[(row0 + 1) * 8] = (u16)(v >> 16);
    }
  }
}

// ---------------- setup: swizzle W51/W71 into d_ws B-frag order ----------------
__global__ void swizzle_ws(Params p) {
  const float* mats[2] = {p.w51, p.w71};
  const int fi = blockIdx.x;   // 0..31
  const int l  = threadIdx.x;
  const int lo = l & 31, hh = l >> 5;
  const float* W = mats[fi >> 4];
  const int t  = (fi >> 3) & 1, c8 = fi & 7;
  const int nn = 32 * t + lo;
  const int k0 = 16 * c8 + 8 * hh;
  u16* dst = p.ws + fi * 512 + l * 8;
#pragma unroll
  for (int j = 0; j < 8; ++j) dst[j] = (u16)f2bf_up(W[(k0 + j) * 64 + nn]);
}

#define NBLK 256
#define NWAVE 8
#define QPW  2   // 256*8*2 = 4096 quads = 16384 graphs

__global__ __launch_bounds__(512)
__attribute__((amdgpu_waves_per_eu(2)))
void hetgnn_mfma(Params p) {
  __shared__ __align__(16) u16   sW[SW_U16];            // 64 KB (7 K=64 mats)
  __shared__ __align__(16) u16   sAct[NWAVE * PW_U16];  // 80 KB
  __shared__ __align__(16) float sConst[CSZ];           // 4.25 KB
  // total 65536 + 81920 + 4352 = 151808 B

  const int tid  = threadIdx.x;
  const int wave = tid >> 6;
  const int l    = tid & 63;
  const int lo   = l & 31;
  const int hh   = l >> 5;

  // ---- stage + swizzle the 7 K=64 matrices into sW (8 frags/wave) ----
  {
    const float* srcs[8] = {p.w61, p.w61 + 64 * 64, p.w52, p.w53,
                            p.w62, p.w63, p.w72, p.w73};
    for (int i = 0; i < 8; ++i) {
      const int fj = wave * 8 + i;           // 0..63, wave-uniform
      const float* W = srcs[fj >> 3];
      const int f2 = fj & 7, t = f2 >> 2, c = f2 & 3;
      const int nn = 32 * t + lo;
      const int k0 = 16 * c + 8 * hh;
      float w[8];
#pragma unroll
      for (int j = 0; j < 8; ++j) w[j] = W[(k0 + j) * 64 + nn];
      uint4 o;
      o.x = pk2(w[0], w[1]); o.y = pk2(w[2], w[3]);
      o.z = pk2(w[4], w[5]); o.w = pk2(w[6], w[7]);
      *(uint4*)(sW + fj * 512 + l * 8) = o;
    }
  }
  if (tid < 64) {
    sConst[CB51 + tid] = p.b51[tid];
    sConst[CB52 + tid] = p.b52[tid];
    sConst[CB53 + tid] = p.b53[tid];
    sConst[CB61 + tid] = p.b61[tid];
    sConst[CB62 + tid] = p.b62[tid];
    sConst[CB63 + tid] = p.b63[tid];
    sConst[CB71 + tid] = p.b71[tid];
    sConst[CB72 + tid] = p.b72[tid];
    sConst[CB73 + tid] = p.b73[tid];
    sConst[CWPA + tid] = p.wpa[tid];
    sConst[CBPA + tid] = p.bpa[tid];
    sConst[CBPE + tid] = p.bpe[tid];
  }
  if (tid < 128) {
    sConst[CWPO + tid] = p.wpost[tid];
    sConst[CWPE + tid] = p.wpe[tid];
  }
  if (tid < 2) sConst[CBPO + tid] = p.bpost[tid];
  __syncthreads();

  // ---- wpost as zero-padded B-frags in regs (cols 0,1 live) ----
  short8_t wpB[4];
#pragma unroll
  for (int c = 0; c < 4; ++c) {
    uint4 v;
    u32 vv[4];
#pragma unroll
    for (int j2 = 0; j2 < 4; ++j2) {
      const int kk = 16 * c + 8 * hh + 2 * j2;
      vv[j2] = (lo < 2) ? pk2(sConst[CWPO + kk * 2 + lo],
                              sConst[CWPO + (kk + 1) * 2 + lo]) : 0u;
    }
    v.x = vv[0]; v.y = vv[1]; v.z = vv[2]; v.w = vv[3];
    wpB[c] = __builtin_bit_cast(short8_t, v);
  }

  u16* M   = sAct + wave * PW_U16;   // eP scratch in-iter; new-e carrier it0->it1
  u16* T1  = M + 2048;
  u16* aPb = M + 4096;               // 1024 u16: 16 dedup rows, b61 folded

  const u16* wsg = p.ws;
  const int wslot = blockIdx.x * NWAVE + wave;

  for (int pi = 0; pi < QPW; ++pi) {
    const int g0 = (wslot * QPW + pi) * 4;   // 4 graphs per quad
    if (g0 + 4 > p.gtot) break;

    // ---------------- pre-layer: a-frags + e-frags in registers ----------------
    // row m = lo: g = lo>>3, b = (lo>>1)&3, k_e = lo&1
    const float apv = p.ap[(g0 + (lo >> 3)) * 4 + ((lo >> 1) & 3)];
    short8_t aA[4], eF[4];
    {
      const float f0 = p.ef[(g0 + (lo >> 3)) * 16 + (lo & 7) * 2];
      const float f1 = p.ef[(g0 + (lo >> 3)) * 16 + (lo & 7) * 2 + 1];
#pragma unroll
      for (int c = 0; c < 4; ++c) {
        const int fb = 16 * c + 8 * hh;
        const float4 wa0 = *(const float4*)(sConst + CWPA + fb);
        const float4 wa1 = *(const float4*)(sConst + CWPA + fb + 4);
        const float4 ba0 = *(const float4*)(sConst + CBPA + fb);
        const float4 ba1 = *(const float4*)(sConst + CBPA + fb + 4);
        uint4 pa;
        pa.x = pk2(fmaxf(fmaf(apv, wa0.x, ba0.x), 0.f), fmaxf(fmaf(apv, wa0.y, ba0.y), 0.f));
        pa.y = pk2(fmaxf(fmaf(apv, wa0.z, ba0.z), 0.f), fmaxf(fmaf(apv, wa0.w, ba0.w), 0.f));
        pa.z = pk2(fmaxf(fmaf(apv, wa1.x, ba1.x), 0.f), fmaxf(fmaf(apv, wa1.y, ba1.y), 0.f));
        pa.w = pk2(fmaxf(fmaf(apv, wa1.z, ba1.z), 0.f), fmaxf(fmaf(apv, wa1.w, ba1.w), 0.f));
        aA[c] = __builtin_bit_cast(short8_t, pa);

        const float4 w00 = *(const float4*)(sConst + CWPE + fb);
        const float4 w01 = *(const float4*)(sConst + CWPE + fb + 4);
        const float4 w10 = *(const float4*)(sConst + CWPE + 64 + fb);
        const float4 w11 = *(const float4*)(sConst + CWPE + 64 + fb + 4);
        const float4 be0 = *(const float4*)(sConst + CBPE + fb);
        const float4 be1 = *(const float4*)(sConst + CBPE + fb + 4);
        uint4 pe;
        pe.x = pk2(fmaxf(fmaf(f0, w00.x, fmaf(f1, w10.x, be0.x)), 0.f),
                   fmaxf(fmaf(f0, w00.y, fmaf(f1, w10.y, be0.y)), 0.f));
        pe.y = pk2(fmaxf(fmaf(f0, w00.z, fmaf(f1, w10.z, be0.z)), 0.f),
                   fmaxf(fmaf(f0, w00.w, fmaf(f1, w10.w, be0.w)), 0.f));
        pe.z = pk2(fmaxf(fmaf(f0, w01.x, fmaf(f1, w11.x, be1.x)), 0.f),
                   fmaxf(fmaf(f0, w01.y, fmaf(f1, w11.y, be1.y)), 0.f));
        pe.w = pk2(fmaxf(fmaf(f0, w01.z, fmaf(f1, w11.z, be1.z)), 0.f),
                   fmaxf(fmaf(f0, w01.w, fmaf(f1, w11.w, be1.w)), 0.f));
        eF[c] = __builtin_bit_cast(short8_t, pe);
      }
    }

    // ---- aP = a @ w61[:64] + b61 (folded), dedup scatter (quad-invariant) ----
    {
      float16v accA[2]; zerov(accA);
      layer64(accA, aA, sW + W61A, l);
#pragma unroll
      for (int t = 0; t < 2; ++t) {
        u16* base = aPb + (2 * t + (lo >> 4)) * 256 + ((lo >> 3) & 1) * 128 + (lo & 7);
        const float bv = sConst[CB61 + 32 * t + lo];
#pragma unroll
        for (int i = 0; i < 8; ++i) {
          const int d = (i >> 1) * 4 + (i & 1) + 2 * hh;   // dedup row of even row(2i)
          base[d * 8] = (u16)f2bf_up(accA[t][2 * i] + bv);
        }
      }
    }

    // ---------------- 2 shared-weight update iterations ----------------
#pragma unroll 1
    for (int it = 0; it < 2; ++it) {
      if (it == 1) gather4(eF, M, l);   // new e from it0 (before M reused as eP)

      // ---- mlp5 -> m1 ----
      u32 m1p[16];
      {
        float16v acc[2]; initv(acc, sConst + CB51, lo);
#pragma unroll
        for (int t = 0; t < 2; ++t)
#pragma unroll
          for (int c8 = 0; c8 < 8; ++c8) {
            const short8_t B = *(const short8_t*)(wsg + (t * 8 + c8) * 512 + l * 8);
            acc[t] = mfma32(c8 < 4 ? aA[c8] : eF[c8 - 4], B, acc[t]);
          }
        scat32<true>(T1, acc, lo, hh);
        short8_t x[4]; gather4(x, T1, l);
        float16v acc2[2]; initv(acc2, sConst + CB52, lo);
        layer64(acc2, x, sW + W52o, l);
        scat32<true>(T1, acc2, lo, hh);
        gather4(x, T1, l);
        float16v acc3[2]; initv(acc3, sConst + CB53, lo);
        layer64(acc3, x, sW + W53o, l);
#pragma unroll
        for (int t = 0; t < 2; ++t)
#pragma unroll
          for (int i = 0; i < 8; ++i)
            m1p[t * 8 + i] = pk2(acc3[t][2 * i], acc3[t][2 * i + 1]);  // raw
      }

      // ---- eP = e @ w61[64:] -> M (A-swizzled, no relu/bias) ----
      {
        float16v accE[2]; zerov(accE);
        layer64(accE, eF, sW + W61B, l);
        scat32<false>(M, accE, lo, hh);
      }

      // ---- mlp6 -> m2: 3 neighbor-tiles, h in regs ----
      u32 m2p[16];
      {
        const int b_ln = (lo >> 1) & 3;
        const int dd   = (lo >> 3) * 4 + b_ln;
#pragma unroll
        for (int j = 0; j < 3; ++j) {
          const int bp = (j >= b_ln) ? (j + 1) : j;
          const int re = (lo & 24) + bp * 2 + (lo & 1);
          short8_t hF[4];
#pragma unroll
          for (int c = 0; c < 4; ++c) {
            const uint4 av = *(const uint4*)(aPb + c * 256 + hh * 128 + dd * 8);
            const uint4 ev = *(const uint4*)(M + c * 512 + hh * 256 + re * 8);
            uint4 ph;   // b61 folded into av
            ph.x = pk2(fmaxf(blo(av.x) + blo(ev.x), 0.f), fmaxf(bhi(av.x) + bhi(ev.x), 0.f));
            ph.y = pk2(fmaxf(blo(av.y) + blo(ev.y), 0.f), fmaxf(bhi(av.y) + bhi(ev.y), 0.f));
            ph.z = pk2(fmaxf(blo(av.z) + blo(ev.z), 0.f), fmaxf(bhi(av.z) + bhi(ev.z), 0.f));
            ph.w = pk2(fmaxf(blo(av.w) + blo(ev.w), 0.f), fmaxf(bhi(av.w) + bhi(ev.w), 0.f));
            hF[c] = __builtin_bit_cast(short8_t, ph);
          }
          float16v acc2[2]; initv(acc2, sConst + CB62, lo);
          layer64(acc2, hF, sW + W62o, l);
          scat32<true>(T1, acc2, lo, hh);
          short8_t x[4]; gather4(x, T1, l);
          float16v acc3[2]; initv(acc3, sConst + CB63, lo);
          layer64(acc3, x, sW + W63o, l);
#pragma unroll
          for (int t = 0; t < 2; ++t)
#pragma unroll
            for (int i = 0; i < 8; ++i) {
              const u32 cand = pk2(acc3[t][2 * i], acc3[t][2 * i + 1]);  // raw
              m2p[t * 8 + i] = (j == 0) ? cand : pkmax(m2p[t * 8 + i], cand);
            }
        }
      }

      // ---- agg = clamp0(max(m1 k-swap, m2)) + mlp7 ----
      {
        u32 agp[16];
#pragma unroll
        for (int i = 0; i < 16; ++i)
          agp[i] = pkmax(pkmax(ror16(m1p[i]), m2p[i]), 0u);
        scatpk32(T1, agp, lo, hh);
        short8_t x[4]; gather4(x, T1, l);
        float16v acc[2]; initv(acc, sConst + CB71, lo);
#pragma unroll
        for (int t = 0; t < 2; ++t)
#pragma unroll
          for (int c8 = 0; c8 < 8; ++c8) {
            const short8_t B = *(const short8_t*)(wsg + (16 + t * 8 + c8) * 512 + l * 8);
            acc[t] = mfma32(c8 < 4 ? x[c8] : eF[c8 - 4], B, acc[t]);
          }
        scat32<true>(T1, acc, lo, hh);
        gather4(x, T1, l);
        float16v acc2[2]; initv(acc2, sConst + CB72, lo);
        layer64(acc2, x, sW + W72o, l);
        scat32<true>(T1, acc2, lo, hh);
        gather4(x, T1, l);
        float16v acc3[2]; initv(acc3, sConst + CB73, lo);
        layer64(acc3, x, sW + W73o, l);

        if (it == 0) {
          scat32<true>(M, acc3, lo, hh);   // new e -> M
        } else {
          // ---- post linear via MFMA (zero-padded wpost B), then L2-norm ----
          scat32<true>(T1, acc3, lo, hh);
          short8_t y[4]; gather4(y, T1, l);
          float16v accP;
#pragma unroll
          for (int i = 0; i < 16; ++i) accP[i] = 0.f;
#pragma unroll
          for (int c = 0; c < 4; ++c) accP = mfma32(y[c], wpB[c], accP);
          // lanes lo=0 hold pr, lo=1 hold pi, for rows row(reg)
          const float bpv = sConst[CBPO + (lo & 1)];
          float myv[16], s2[16];
#pragma unroll
          for (int r = 0; r < 16; ++r) {
            myv[r] = accP[r] + bpv;
            const float oth = __shfl_xor(myv[r], 1, 64);
            s2[r] = myv[r] * myv[r] + oth * oth;
          }
          if (lo < 2) {
#pragma unroll
            for (int r = 0; r < 16; ++r) {
              const float n2 = s2[r] + s2[r ^ 1];   // rows m, m^1 (k pair)
              p.out[(g0 + (r >> 2)) * 16 + ((r & 3) + 4 * hh) * 2 + lo] =
                  myv[r] / sqrtf(n2);
            }
          }
        }
      }
    }
  }
}

extern "C" void kernel_launch(void* const* d_in, const int* in_sizes, int n_in,
                              void* d_out, int out_size, void* d_ws, size_t ws_size,
                              hipStream_t stream) {
  Params p;
  p.ap    = (const float*)d_in[0];
  p.ef    = (const float*)d_in[1];
  p.wpa   = (const float*)d_in[2];  p.bpa   = (const float*)d_in[3];
  p.wpe   = (const float*)d_in[4];  p.bpe   = (const float*)d_in[5];
  p.w51   = (const float*)d_in[6];  p.b51   = (const float*)d_in[7];
  p.w52   = (const float*)d_in[8];  p.b52   = (const float*)d_in[9];
  p.w53   = (const float*)d_in[10]; p.b53   = (const float*)d_in[11];
  p.w61   = (const float*)d_in[12]; p.b61   = (const float*)d_in[13];
  p.w62   = (const float*)d_in[14]; p.b62   = (const float*)d_in[15];
  p.w63   = (const float*)d_in[16]; p.b63   = (const float*)d_in[17];
  p.w71   = (const float*)d_in[18]; p.b71   = (const float*)d_in[19];
  p.w72   = (const float*)d_in[20]; p.b72   = (const float*)d_in[21];
  p.w73   = (const float*)d_in[22]; p.b73   = (const float*)d_in[23];
  p.wpost = (const float*)d_in[24]; p.bpost = (const float*)d_in[25];
  p.out   = (float*)d_out;
  p.ws    = (u16*)d_ws;
  p.gtot  = in_sizes[0] / 4;  // G from ap_feat [G,B,1]

  hipLaunchKernelGGL(swizzle_ws, dim3(32), dim3(64), 0, stream, p);
  hipLaunchKernelGGL(hetgnn_mfma, dim3(NBLK), dim3(512), 0, stream, p);
}